// Round 4
// baseline (5264.446 us; speedup 1.0000x reference)
//
#include <hip/hip_runtime.h>
#include <stdint.h>

#define S_DIM 32
#define B_DIM 64
#define N_DIM 2048
#define F_DIM 16
#define E_DIM 32768
#define H_DIM 512
#define H3 1536
#define SB 2048
#define EPS_BN 1e-5f
#define GRUB 256   // persistent GRU grid (<= 256 CUs, co-resident)

typedef __attribute__((ext_vector_type(4))) float f32x4;
typedef __attribute__((ext_vector_type(8))) __bf16 bf16x8;

static __device__ __forceinline__ unsigned short f2bf(float f) {
    union { float f; unsigned int u; } v; v.f = f;
    unsigned int r = v.u + 0x7FFFu + ((v.u >> 16) & 1u);
    return (unsigned short)(r >> 16);
}

// ---------------- GCN stage 1: z[n][sb] = dot(x[sb,n,:], W1) ----------------
__global__ __launch_bounds__(256) void k_gcn1_dot(const float* __restrict__ x,
        const float* __restrict__ W1, float* __restrict__ z) {
    __shared__ float tile[64][65];
    int bn = blockIdx.x & 31;
    int bs = blockIdx.x >> 5;
    int n0 = bn * 64, sb0 = bs * 64;
    float4 w0 = *(const float4*)&W1[0];
    float4 w1 = *(const float4*)&W1[4];
    float4 w2 = *(const float4*)&W1[8];
    float4 w3 = *(const float4*)&W1[12];
    int t = threadIdx.x;
    for (int i = 0; i < 16; ++i) {
        int idx = t + 256 * i;
        int nl = idx & 63, sl = idx >> 6;
        const float4* xv = (const float4*)(x + ((size_t)(sb0 + sl) * N_DIM + (n0 + nl)) * F_DIM);
        float4 a = xv[0], b = xv[1], c = xv[2], d = xv[3];
        float acc = a.x*w0.x + a.y*w0.y + a.z*w0.z + a.w*w0.w
                  + b.x*w1.x + b.y*w1.y + b.z*w1.z + b.w*w1.w
                  + c.x*w2.x + c.y*w2.y + c.z*w2.z + c.w*w2.w
                  + d.x*w3.x + d.y*w3.y + d.z*w3.z + d.w*w3.w;
        tile[nl][sl] = acc;
    }
    __syncthreads();
    for (int i = 0; i < 16; ++i) {
        int idx = t + 256 * i;
        int sl = idx & 63, nl = idx >> 6;
        z[(size_t)(n0 + nl) * SB + sb0 + sl] = tile[nl][sl];
    }
}

// ---------------- CSR build ----------------
__global__ void k_degcnt(const int* __restrict__ ei, int* __restrict__ cnt) {
    int e = blockIdx.x * 256 + threadIdx.x;
    if (e < E_DIM) atomicAdd(&cnt[ei[E_DIM + e]], 1);
}
__global__ void k_dinv(const int* __restrict__ cnt, float* __restrict__ dinv) {
    int n = blockIdx.x * 256 + threadIdx.x;
    if (n < N_DIM) dinv[n] = rsqrtf(1.0f + (float)cnt[n]);
}
__global__ void k_scan(const int* __restrict__ cnt, int* __restrict__ rowptr) {
    __shared__ int sc[2048];
    int t = threadIdx.x;
    sc[t] = cnt[t]; sc[t + 1024] = cnt[t + 1024];
    __syncthreads();
    for (int off = 1; off < 2048; off <<= 1) {
        int a = (t >= off) ? sc[t - off] : 0;
        int b = (t + 1024 >= off) ? sc[t + 1024 - off] : 0;
        __syncthreads();
        sc[t] += a; sc[t + 1024] += b;
        __syncthreads();
    }
    rowptr[t] = sc[t] - cnt[t];
    rowptr[t + 1024] = sc[t + 1024] - cnt[t + 1024];
    if (t == 0) rowptr[2048] = E_DIM;
}
__global__ void k_fill(const int* __restrict__ ei, const int* __restrict__ rowptr,
                       int* __restrict__ cursor, int* __restrict__ cols) {
    int e = blockIdx.x * 256 + threadIdx.x;
    if (e < E_DIM) {
        int d = ei[E_DIM + e];
        int pos = atomicAdd(&cursor[d], 1);
        cols[rowptr[d] + pos] = ei[e];
    }
}

// ---------------- SpMM (gather). mode0: sigmoid(acc+b1). mode1: BN(w2*acc+b2) ----------------
__global__ __launch_bounds__(256) void k_spmm(const float* __restrict__ in,
        float* __restrict__ outp, const int* __restrict__ rowptr, const int* __restrict__ cols,
        const float* __restrict__ dinv, int mode,
        const float* __restrict__ bp, const float* __restrict__ w2p,
        const float* __restrict__ gamma, const float* __restrict__ beta,
        const float* __restrict__ rmean, const float* __restrict__ rvar) {
    int n = blockIdx.x & 2047;
    int sb = ((blockIdx.x >> 11) << 8) + threadIdx.x;
    float dn = dinv[n];
    float acc = dn * dn * in[(size_t)n * SB + sb];
    int i0 = rowptr[n], i1 = rowptr[n + 1];
    for (int idx = i0; idx < i1; ++idx) {
        int s = cols[idx];
        acc += dn * dinv[s] * in[(size_t)s * SB + sb];
    }
    float v;
    if (mode == 0) {
        v = acc + bp[0];
        v = 1.0f / (1.0f + __expf(-v));
    } else {
        v = w2p[0] * acc + bp[0];
        v = (v - rmean[n]) * rsqrtf(rvar[n] + EPS_BN) * gamma[n] + beta[n];
    }
    outp[(size_t)n * SB + sb] = v;
}

// ---------------- transpose + fp32->bf16: in (R,C) f32 -> out (C,R) bf16 ----------------
__global__ __launch_bounds__(256) void k_transpose_cvt(const float* __restrict__ in,
        unsigned short* __restrict__ outp, int R, int C) {
    __shared__ float tile[64][65];
    int nrt = R >> 6;
    int rt = blockIdx.x % nrt;
    int ct = blockIdx.x / nrt;
    int r0 = rt * 64, c0 = ct * 64;
    int t = threadIdx.x;
    for (int i = 0; i < 16; ++i) {
        int idx = t + i * 256;
        int cl = idx & 63, rl = idx >> 6;
        tile[rl][cl] = in[(size_t)(r0 + rl) * C + c0 + cl];
    }
    __syncthreads();
    for (int i = 0; i < 16; ++i) {
        int idx = t + i * 256;
        int rl = idx & 63, cl = idx >> 6;
        outp[(size_t)(c0 + cl) * R + r0 + rl] = f2bf(tile[rl][cl]);
    }
}

// ---------------- transpose f32: in (R,C) -> out (C,R) ----------------
__global__ __launch_bounds__(256) void k_transpose_f32(const float* __restrict__ in,
        float* __restrict__ outp, int R, int C) {
    __shared__ float tile[64][65];
    int nrt = R >> 6;
    int rt = blockIdx.x % nrt;
    int ct = blockIdx.x / nrt;
    int r0 = rt * 64, c0 = ct * 64;
    int t = threadIdx.x;
    for (int i = 0; i < 16; ++i) {
        int idx = t + i * 256;
        int cl = idx & 63, rl = idx >> 6;
        tile[rl][cl] = in[(size_t)(r0 + rl) * C + c0 + cl];
    }
    __syncthreads();
    for (int i = 0; i < 16; ++i) {
        int idx = t + i * 256;
        int rl = idx & 63, cl = idx >> 6;
        outp[(size_t)(c0 + cl) * R + r0 + rl] = tile[rl][cl];
    }
}

// ---------------- elementwise fp32 -> bf16 ----------------
__global__ void k_cvt_bf16(const float* __restrict__ in, unsigned short* __restrict__ outp, int nelem) {
    int i = (blockIdx.x * 256 + threadIdx.x) * 4;
    if (i < nelem) {
        float4 v = *(const float4*)&in[i];
        ushort4 o;
        o.x = f2bf(v.x); o.y = f2bf(v.y); o.z = f2bf(v.z); o.w = f2bf(v.w);
        *(ushort4*)&outp[i] = o;
    }
}

// ---------------- bf16 MFMA GEMM: C(M,N) = A(M,K)*B(N,K)^T + bias(N), 128x64 tile ----------------
#define BM 128
#define BN 64
#define BKK 32
#define LDT 40

__global__ __launch_bounds__(256) void k_gemm_bf16(
        const unsigned short* __restrict__ A,
        const unsigned short* __restrict__ Bm,
        const float* __restrict__ bias,
        float* __restrict__ Cm, int M, int N, int K) {
    __shared__ __align__(16) unsigned short lA[BM * LDT];
    __shared__ __align__(16) unsigned short lB[BN * LDT];
    int mtiles = M / BM;
    int mt = blockIdx.x % mtiles;
    int nt = blockIdx.x / mtiles;
    int m0 = mt * BM, n0 = nt * BN;
    int t = threadIdx.x;
    int wave = t >> 6, lane = t & 63;
    int wm = (wave >> 1) * 64, wn = (wave & 1) * 32;
    int lrow = lane & 15, lk = (lane >> 4) * 8;
    int srowA = t >> 1, scolA = (t & 1) * 16;
    int srowB = t >> 2, scolB = (t & 3) * 8;
    f32x4 acc[4][2] = {};
    for (int k0 = 0; k0 < K; k0 += BKK) {
        const unsigned short* ga = A  + (size_t)(m0 + srowA) * K + k0 + scolA;
        const unsigned short* gb = Bm + (size_t)(n0 + srowB) * K + k0 + scolB;
        *(uint4*)&lA[srowA * LDT + scolA]     = *(const uint4*)ga;
        *(uint4*)&lA[srowA * LDT + scolA + 8] = *(const uint4*)(ga + 8);
        *(uint4*)&lB[srowB * LDT + scolB]     = *(const uint4*)gb;
        __syncthreads();
        bf16x8 af[4], bg[2];
        #pragma unroll
        for (int i = 0; i < 4; ++i)
            af[i] = *(const bf16x8*)&lA[(wm + i * 16 + lrow) * LDT + lk];
        #pragma unroll
        for (int j = 0; j < 2; ++j)
            bg[j] = *(const bf16x8*)&lB[(wn + j * 16 + lrow) * LDT + lk];
        #pragma unroll
        for (int i = 0; i < 4; ++i)
            #pragma unroll
            for (int j = 0; j < 2; ++j)
                acc[i][j] = __builtin_amdgcn_mfma_f32_16x16x32_bf16(af[i], bg[j], acc[i][j], 0, 0, 0);
        __syncthreads();
    }
    int crow = (lane >> 4) * 4, ccol = lane & 15;
    #pragma unroll
    for (int i = 0; i < 4; ++i)
        #pragma unroll
        for (int j = 0; j < 2; ++j) {
            int gn = n0 + wn + j * 16 + ccol;
            float bv = bias[gn];
            #pragma unroll
            for (int r = 0; r < 4; ++r) {
                int gm = m0 + wm + i * 16 + crow + r;
                Cm[(size_t)gm * N + gn] = acc[i][j][r] + bv;
            }
        }
}

// ---------------- persistent GRU layer: 32 steps in one launch ----------------
// grid = 256 blocks x 512 threads. block owns jh = blk*2 + {0,1}; waves split K 4-way.
// h layout: (H/4, B, 4) f32 so dot-loop loads are coalesced float4 per (k4, b-lane).
// giT: (3H, SB) f32 (bih already added by GEMM bias).
__global__ __launch_bounds__(512, 4) void k_gru_layer(
        const float* __restrict__ giT,
        const float* __restrict__ Whh,
        const float* __restrict__ bhh,
        float* __restrict__ hbufA,       // zeroed before launch (t=0 reads it)
        float* __restrict__ hbufB,
        float* __restrict__ yT,          // (H, SB)
        float* __restrict__ hn_out,      // (B, H) final h
        int* __restrict__ bar) {         // zeroed before launch
    __shared__ float wlds[2 * 3 * 512];  // [jl][gate][k] 12 KB
    __shared__ float red[3][8][66];
    int tid = threadIdx.x;
    int lane = tid & 63;
    int w = tid >> 6;            // 0..7
    int jl = w & 1;
    int kq = w >> 1;             // 0..3
    int jh = blockIdx.x * 2 + jl;
    // stage Whh rows for this block's 2 jh (once, reused for all 32 steps)
    for (int r_ = 0; r_ < 6; ++r_) {
        int jl2 = r_ & 1, g = r_ >> 1;
        wlds[(jl2 * 3 + g) * 512 + tid] =
            Whh[(size_t)(g * 512 + blockIdx.x * 2 + jl2) * H_DIM + tid];
    }
    __syncthreads();
    float br = bhh[jh], bz = bhh[512 + jh], bn = bhh[1024 + jh];
    const f32x4* wr4 = (const f32x4*)&wlds[(jl * 3 + 0) * 512 + kq * 128];
    const f32x4* wz4 = (const f32x4*)&wlds[(jl * 3 + 1) * 512 + kq * 128];
    const f32x4* wn4 = (const f32x4*)&wlds[(jl * 3 + 2) * 512 + kq * 128];
    for (int t = 0; t < 32; ++t) {
        const float* hr = (t & 1) ? hbufB : hbufA;
        float* hw = (t & 1) ? hbufA : hbufB;
        const f32x4* h4 = (const f32x4*)hr + kq * 2048 + lane;
        float accr = 0.f, accz = 0.f, accn = 0.f;
        #pragma unroll
        for (int q = 0; q < 32; ++q) {
            f32x4 hv = h4[q * 64];
            f32x4 vr = wr4[q], vz = wz4[q], vn = wn4[q];
            accr += hv.x*vr.x + hv.y*vr.y + hv.z*vr.z + hv.w*vr.w;
            accz += hv.x*vz.x + hv.y*vz.y + hv.z*vz.z + hv.w*vz.w;
            accn += hv.x*vn.x + hv.y*vn.y + hv.z*vn.z + hv.w*vn.w;
        }
        red[0][w][lane] = accr; red[1][w][lane] = accz; red[2][w][lane] = accn;
        __syncthreads();
        if (w < 2) {
            float ar = red[0][w][lane] + red[0][w+2][lane] + red[0][w+4][lane] + red[0][w+6][lane];
            float az = red[1][w][lane] + red[1][w+2][lane] + red[1][w+4][lane] + red[1][w+6][lane];
            float an = red[2][w][lane] + red[2][w+2][lane] + red[2][w+4][lane] + red[2][w+6][lane];
            float hp = hr[((jh >> 2) * 64 + lane) * 4 + (jh & 3)];
            float gr = giT[(size_t)jh * SB + t * 64 + lane];
            float gz = giT[(size_t)(512 + jh) * SB + t * 64 + lane];
            float gn = giT[(size_t)(1024 + jh) * SB + t * 64 + lane];
            float rr = 1.0f / (1.0f + __expf(-(gr + ar + br)));
            float zz = 1.0f / (1.0f + __expf(-(gz + az + bz)));
            float nn = tanhf(gn + rr * (an + bn));
            float h = (1.0f - zz) * nn + zz * hp;
            hw[((jh >> 2) * 64 + lane) * 4 + (jh & 3)] = h;
            yT[(size_t)jh * SB + t * 64 + lane] = h;
            if (t == 31) hn_out[lane * H_DIM + jh] = h;
        }
        // grid-wide barrier: release writes -> arrive -> spin -> acquire
        __syncthreads();           // drains this block's stores (vmcnt)
        __threadfence();           // release: write back to coherence point
        if (tid == 0) {
            atomicAdd(bar, 1);
            int tgt = (t + 1) * GRUB;
            while (__hip_atomic_load(bar, __ATOMIC_RELAXED, __HIP_MEMORY_SCOPE_AGENT) < tgt) {
                __builtin_amdgcn_s_sleep(1);
            }
        }
        __syncthreads();
        __threadfence();           // acquire: invalidate stale L1/L2 before reading new h
    }
}

// ---------------- final linear: out[sb] = dot(y2T[:,sb], Wlin) + blin ----------------
__global__ void k_final(const float* __restrict__ y2T, const float* __restrict__ Wlin,
                        const float* __restrict__ blin, float* __restrict__ outp) {
    int sb = blockIdx.x * 256 + threadIdx.x;
    float acc = blin[0];
    for (int k = 0; k < H_DIM; ++k)
        acc += y2T[(size_t)k * SB + sb] * Wlin[k];
    outp[sb] = acc;
}

extern "C" void kernel_launch(void* const* d_in, const int* in_sizes, int n_in,
                              void* d_out, int out_size, void* d_ws, size_t ws_size,
                              hipStream_t stream) {
    (void)in_sizes; (void)n_in; (void)out_size; (void)ws_size;
    const float* x     = (const float*)d_in[0];
    const int*   ei    = (const int*)d_in[1];
    const float* W1    = (const float*)d_in[2];
    const float* b1    = (const float*)d_in[3];
    const float* W2    = (const float*)d_in[4];
    const float* b2    = (const float*)d_in[5];
    const float* gamma = (const float*)d_in[6];
    const float* beta  = (const float*)d_in[7];
    const float* rmean = (const float*)d_in[8];
    const float* rvar  = (const float*)d_in[9];
    const float* Wih0  = (const float*)d_in[10];
    const float* Whh0  = (const float*)d_in[11];
    const float* bih0  = (const float*)d_in[12];
    const float* bhh0  = (const float*)d_in[13];
    const float* Wih1  = (const float*)d_in[14];
    const float* Whh1  = (const float*)d_in[15];
    const float* bih1  = (const float*)d_in[16];
    const float* bhh1  = (const float*)d_in[17];
    const float* Wlin  = (const float*)d_in[18];
    const float* blin  = (const float*)d_in[19];
    float* outp = (float*)d_out;

    char* w = (char*)d_ws;
    auto alloc = [&](size_t bytes) { char* p = w; w += (bytes + 255) & ~(size_t)255; return p; };
    float*          zbuf   = (float*)alloc((size_t)N_DIM * SB * 4);   // z -> oT -> gi0
    float*          h1buf  = (float*)alloc((size_t)N_DIM * SB * 4);   // h1 -> o_bf16 -> gi1
    float*          giT    = (float*)alloc((size_t)H3 * SB * 4);      // transposed gates
    unsigned short* wih0b  = (unsigned short*)alloc((size_t)H3 * N_DIM * 2);
    unsigned short* wih1b  = (unsigned short*)alloc((size_t)H3 * H_DIM * 2);
    float*          y1T    = (float*)alloc((size_t)H_DIM * SB * 4);   // also y2T
    unsigned short* y1b    = (unsigned short*)alloc((size_t)SB * H_DIM * 2);
    float*          hA4    = (float*)alloc(B_DIM * H_DIM * 4);
    float*          hB4    = (float*)alloc(B_DIM * H_DIM * 4);
    float*          dinv   = (float*)alloc(N_DIM * 4);
    int*            degcnt = (int*)alloc(N_DIM * 4);
    int*            rowptr = (int*)alloc((N_DIM + 1) * 4);
    int*            cursor = (int*)alloc(N_DIM * 4);
    int*            cols   = (int*)alloc(E_DIM * 4);
    int*            bar0   = (int*)alloc(256);
    int*            bar1   = (int*)alloc(256);
    unsigned short* obf    = (unsigned short*)h1buf;

    hipMemsetAsync(degcnt, 0, N_DIM * 4, stream);
    hipMemsetAsync(cursor, 0, N_DIM * 4, stream);
    hipMemsetAsync(hA4, 0, B_DIM * H_DIM * 4, stream);
    hipMemsetAsync(bar0, 0, 256, stream);
    hipMemsetAsync(bar1, 0, 256, stream);

    k_gcn1_dot<<<1024, 256, 0, stream>>>(x, W1, zbuf);
    k_degcnt<<<E_DIM / 256, 256, 0, stream>>>(ei, degcnt);
    k_dinv<<<N_DIM / 256, 256, 0, stream>>>(degcnt, dinv);
    k_scan<<<1, 1024, 0, stream>>>(degcnt, rowptr);
    k_fill<<<E_DIM / 256, 256, 0, stream>>>(ei, rowptr, cursor, cols);

    k_spmm<<<16384, 256, 0, stream>>>(zbuf, h1buf, rowptr, cols, dinv, 0, b1, (const float*)nullptr,
                                      gamma, beta, rmean, rvar);
    k_spmm<<<16384, 256, 0, stream>>>(h1buf, zbuf, rowptr, cols, dinv, 1, b2, W2,
                                      gamma, beta, rmean, rvar);
    // oT (N,SB) f32 -> o (SB,N) bf16
    k_transpose_cvt<<<(N_DIM / 64) * (SB / 64), 256, 0, stream>>>(zbuf, obf, N_DIM, SB);
    k_cvt_bf16<<<(H3 * N_DIM / 4) / 256, 256, 0, stream>>>(Wih0, wih0b, H3 * N_DIM);
    k_cvt_bf16<<<(H3 * H_DIM / 4) / 256, 256, 0, stream>>>(Wih1, wih1b, H3 * H_DIM);

    // gi0 = o @ Wih0^T + bih0   (SB, 3H), then transpose -> giT (3H, SB)
    float* gi0 = zbuf;
    k_gemm_bf16<<<(SB / BM) * (H3 / BN), 256, 0, stream>>>(obf, wih0b, bih0, gi0, SB, H3, N_DIM);
    k_transpose_f32<<<(SB / 64) * (H3 / 64), 256, 0, stream>>>(gi0, giT, SB, H3);

    k_gru_layer<<<GRUB, 512, 0, stream>>>(giT, Whh0, bhh0, hA4, hB4, y1T, outp + 2048, bar0);

    // y1T (H,SB) f32 -> y1 (SB,H) bf16; gi1 = y1 @ Wih1^T + bih1; transpose
    k_transpose_cvt<<<(H_DIM / 64) * (SB / 64), 256, 0, stream>>>(y1T, y1b, H_DIM, SB);
    float* gi1 = h1buf;
    k_gemm_bf16<<<(SB / BM) * (H3 / BN), 256, 0, stream>>>(y1b, wih1b, bih1, gi1, SB, H3, H_DIM);
    k_transpose_f32<<<(SB / 64) * (H3 / 64), 256, 0, stream>>>(gi1, giT, SB, H3);

    hipMemsetAsync(hA4, 0, B_DIM * H_DIM * 4, stream);
    k_gru_layer<<<GRUB, 512, 0, stream>>>(giT, Whh1, bhh1, hA4, hB4, y1T, outp + 2048 + 32768, bar1);

    k_final<<<SB / 256, 256, 0, stream>>>(y1T, Wlin, blin, outp);
}

// Round 6
// 1180.588 us; speedup vs baseline: 4.4592x; 4.4592x over previous
//
#include <hip/hip_runtime.h>
#include <stdint.h>

#define S_DIM 32
#define B_DIM 64
#define N_DIM 2048
#define F_DIM 16
#define E_DIM 32768
#define H_DIM 512
#define H3 1536
#define SB 2048
#define EPS_BN 1e-5f
#define GRUB 256   // persistent GRU grid; must be <= 256 so all blocks are co-resident

typedef __attribute__((ext_vector_type(4))) float f32x4;
typedef __attribute__((ext_vector_type(8))) __bf16 bf16x8;

static __device__ __forceinline__ unsigned short f2bf(float f) {
    union { float f; unsigned int u; } v; v.f = f;
    unsigned int r = v.u + 0x7FFFu + ((v.u >> 16) & 1u);
    return (unsigned short)(r >> 16);
}

// coherent (agent-scope, cache-bypassing) scalar load/store: sc0 sc1 = go to coherence point
#define HLD(dst, base, OFF) \
    asm volatile("global_load_dword %0, %1, off offset:" #OFF " sc0 sc1" : "=v"(dst) : "v"(base))
#define HLD16(A, I, base) \
    HLD(A[I+0],base,0);    HLD(A[I+1],base,256);  HLD(A[I+2],base,512);  HLD(A[I+3],base,768); \
    HLD(A[I+4],base,1024); HLD(A[I+5],base,1280); HLD(A[I+6],base,1536); HLD(A[I+7],base,1792); \
    HLD(A[I+8],base,2048); HLD(A[I+9],base,2304); HLD(A[I+10],base,2560);HLD(A[I+11],base,2816);\
    HLD(A[I+12],base,3072);HLD(A[I+13],base,3328);HLD(A[I+14],base,3584);HLD(A[I+15],base,3840)
#define HST(val, addr) \
    asm volatile("global_store_dword %0, %1, off sc0 sc1" :: "v"(addr), "v"(val) : "memory")

// ---------------- GCN stage 1: z[n][sb] = dot(x[sb,n,:], W1) ----------------
__global__ __launch_bounds__(256) void k_gcn1_dot(const float* __restrict__ x,
        const float* __restrict__ W1, float* __restrict__ z) {
    __shared__ float tile[64][65];
    int bn = blockIdx.x & 31;
    int bs = blockIdx.x >> 5;
    int n0 = bn * 64, sb0 = bs * 64;
    float4 w0 = *(const float4*)&W1[0];
    float4 w1 = *(const float4*)&W1[4];
    float4 w2 = *(const float4*)&W1[8];
    float4 w3 = *(const float4*)&W1[12];
    int t = threadIdx.x;
    for (int i = 0; i < 16; ++i) {
        int idx = t + 256 * i;
        int nl = idx & 63, sl = idx >> 6;
        const float4* xv = (const float4*)(x + ((size_t)(sb0 + sl) * N_DIM + (n0 + nl)) * F_DIM);
        float4 a = xv[0], b = xv[1], c = xv[2], d = xv[3];
        float acc = a.x*w0.x + a.y*w0.y + a.z*w0.z + a.w*w0.w
                  + b.x*w1.x + b.y*w1.y + b.z*w1.z + b.w*w1.w
                  + c.x*w2.x + c.y*w2.y + c.z*w2.z + c.w*w2.w
                  + d.x*w3.x + d.y*w3.y + d.z*w3.z + d.w*w3.w;
        tile[nl][sl] = acc;
    }
    __syncthreads();
    for (int i = 0; i < 16; ++i) {
        int idx = t + 256 * i;
        int sl = idx & 63, nl = idx >> 6;
        z[(size_t)(n0 + nl) * SB + sb0 + sl] = tile[nl][sl];
    }
}

// ---------------- CSR build ----------------
__global__ void k_degcnt(const int* __restrict__ ei, int* __restrict__ cnt) {
    int e = blockIdx.x * 256 + threadIdx.x;
    if (e < E_DIM) atomicAdd(&cnt[ei[E_DIM + e]], 1);
}
__global__ void k_dinv(const int* __restrict__ cnt, float* __restrict__ dinv) {
    int n = blockIdx.x * 256 + threadIdx.x;
    if (n < N_DIM) dinv[n] = rsqrtf(1.0f + (float)cnt[n]);
}
__global__ void k_scan(const int* __restrict__ cnt, int* __restrict__ rowptr) {
    __shared__ int sc[2048];
    int t = threadIdx.x;
    sc[t] = cnt[t]; sc[t + 1024] = cnt[t + 1024];
    __syncthreads();
    for (int off = 1; off < 2048; off <<= 1) {
        int a = (t >= off) ? sc[t - off] : 0;
        int b = (t + 1024 >= off) ? sc[t + 1024 - off] : 0;
        __syncthreads();
        sc[t] += a; sc[t + 1024] += b;
        __syncthreads();
    }
    rowptr[t] = sc[t] - cnt[t];
    rowptr[t + 1024] = sc[t + 1024] - cnt[t + 1024];
    if (t == 0) rowptr[2048] = E_DIM;
}
__global__ void k_fill(const int* __restrict__ ei, const int* __restrict__ rowptr,
                       int* __restrict__ cursor, int* __restrict__ cols) {
    int e = blockIdx.x * 256 + threadIdx.x;
    if (e < E_DIM) {
        int d = ei[E_DIM + e];
        int pos = atomicAdd(&cursor[d], 1);
        cols[rowptr[d] + pos] = ei[e];
    }
}

// ---------------- SpMM (gather). mode0: sigmoid(acc+b1). mode1: BN(w2*acc+b2) ----------------
__global__ __launch_bounds__(256) void k_spmm(const float* __restrict__ in,
        float* __restrict__ outp, const int* __restrict__ rowptr, const int* __restrict__ cols,
        const float* __restrict__ dinv, int mode,
        const float* __restrict__ bp, const float* __restrict__ w2p,
        const float* __restrict__ gamma, const float* __restrict__ beta,
        const float* __restrict__ rmean, const float* __restrict__ rvar) {
    int n = blockIdx.x & 2047;
    int sb = ((blockIdx.x >> 11) << 8) + threadIdx.x;
    float dn = dinv[n];
    float acc = dn * dn * in[(size_t)n * SB + sb];
    int i0 = rowptr[n], i1 = rowptr[n + 1];
    for (int idx = i0; idx < i1; ++idx) {
        int s = cols[idx];
        acc += dn * dinv[s] * in[(size_t)s * SB + sb];
    }
    float v;
    if (mode == 0) {
        v = acc + bp[0];
        v = 1.0f / (1.0f + __expf(-v));
    } else {
        v = w2p[0] * acc + bp[0];
        v = (v - rmean[n]) * rsqrtf(rvar[n] + EPS_BN) * gamma[n] + beta[n];
    }
    outp[(size_t)n * SB + sb] = v;
}

// ---------------- transpose + fp32->bf16: in (R,C) f32 -> out (C,R) bf16 ----------------
__global__ __launch_bounds__(256) void k_transpose_cvt(const float* __restrict__ in,
        unsigned short* __restrict__ outp, int R, int C) {
    __shared__ float tile[64][65];
    int nrt = R >> 6;
    int rt = blockIdx.x % nrt;
    int ct = blockIdx.x / nrt;
    int r0 = rt * 64, c0 = ct * 64;
    int t = threadIdx.x;
    for (int i = 0; i < 16; ++i) {
        int idx = t + i * 256;
        int cl = idx & 63, rl = idx >> 6;
        tile[rl][cl] = in[(size_t)(r0 + rl) * C + c0 + cl];
    }
    __syncthreads();
    for (int i = 0; i < 16; ++i) {
        int idx = t + i * 256;
        int rl = idx & 63, cl = idx >> 6;
        outp[(size_t)(c0 + cl) * R + r0 + rl] = f2bf(tile[rl][cl]);
    }
}

// ---------------- transpose f32: in (R,C) -> out (C,R) ----------------
__global__ __launch_bounds__(256) void k_transpose_f32(const float* __restrict__ in,
        float* __restrict__ outp, int R, int C) {
    __shared__ float tile[64][65];
    int nrt = R >> 6;
    int rt = blockIdx.x % nrt;
    int ct = blockIdx.x / nrt;
    int r0 = rt * 64, c0 = ct * 64;
    int t = threadIdx.x;
    for (int i = 0; i < 16; ++i) {
        int idx = t + i * 256;
        int cl = idx & 63, rl = idx >> 6;
        tile[rl][cl] = in[(size_t)(r0 + rl) * C + c0 + cl];
    }
    __syncthreads();
    for (int i = 0; i < 16; ++i) {
        int idx = t + i * 256;
        int rl = idx & 63, cl = idx >> 6;
        outp[(size_t)(c0 + cl) * R + r0 + rl] = tile[rl][cl];
    }
}

// ---------------- elementwise fp32 -> bf16 ----------------
__global__ void k_cvt_bf16(const float* __restrict__ in, unsigned short* __restrict__ outp, int nelem) {
    int i = (blockIdx.x * 256 + threadIdx.x) * 4;
    if (i < nelem) {
        float4 v = *(const float4*)&in[i];
        ushort4 o;
        o.x = f2bf(v.x); o.y = f2bf(v.y); o.z = f2bf(v.z); o.w = f2bf(v.w);
        *(ushort4*)&outp[i] = o;
    }
}

// ---------------- bf16 MFMA GEMM: C(M,N) = A(M,K)*B(N,K)^T + bias(N), 128x64 tile ----------------
#define BM 128
#define BN 64
#define BKK 32
#define LDT 40

__global__ __launch_bounds__(256) void k_gemm_bf16(
        const unsigned short* __restrict__ A,
        const unsigned short* __restrict__ Bm,
        const float* __restrict__ bias,
        float* __restrict__ Cm, int M, int N, int K) {
    __shared__ __align__(16) unsigned short lA[BM * LDT];
    __shared__ __align__(16) unsigned short lB[BN * LDT];
    int mtiles = M / BM;
    int mt = blockIdx.x % mtiles;
    int nt = blockIdx.x / mtiles;
    int m0 = mt * BM, n0 = nt * BN;
    int t = threadIdx.x;
    int wave = t >> 6, lane = t & 63;
    int wm = (wave >> 1) * 64, wn = (wave & 1) * 32;
    int lrow = lane & 15, lk = (lane >> 4) * 8;
    int srowA = t >> 1, scolA = (t & 1) * 16;
    int srowB = t >> 2, scolB = (t & 3) * 8;
    f32x4 acc[4][2] = {};
    for (int k0 = 0; k0 < K; k0 += BKK) {
        const unsigned short* ga = A  + (size_t)(m0 + srowA) * K + k0 + scolA;
        const unsigned short* gb = Bm + (size_t)(n0 + srowB) * K + k0 + scolB;
        *(uint4*)&lA[srowA * LDT + scolA]     = *(const uint4*)ga;
        *(uint4*)&lA[srowA * LDT + scolA + 8] = *(const uint4*)(ga + 8);
        *(uint4*)&lB[srowB * LDT + scolB]     = *(const uint4*)gb;
        __syncthreads();
        bf16x8 af[4], bg[2];
        #pragma unroll
        for (int i = 0; i < 4; ++i)
            af[i] = *(const bf16x8*)&lA[(wm + i * 16 + lrow) * LDT + lk];
        #pragma unroll
        for (int j = 0; j < 2; ++j)
            bg[j] = *(const bf16x8*)&lB[(wn + j * 16 + lrow) * LDT + lk];
        #pragma unroll
        for (int i = 0; i < 4; ++i)
            #pragma unroll
            for (int j = 0; j < 2; ++j)
                acc[i][j] = __builtin_amdgcn_mfma_f32_16x16x32_bf16(af[i], bg[j], acc[i][j], 0, 0, 0);
        __syncthreads();
    }
    int crow = (lane >> 4) * 4, ccol = lane & 15;
    #pragma unroll
    for (int i = 0; i < 4; ++i)
        #pragma unroll
        for (int j = 0; j < 2; ++j) {
            int gn = n0 + wn + j * 16 + ccol;
            float bv = bias[gn];
            #pragma unroll
            for (int r = 0; r < 4; ++r) {
                int gm = m0 + wm + i * 16 + crow + r;
                Cm[(size_t)gm * N + gn] = acc[i][j][r] + bv;
            }
        }
}

// ---------------- persistent GRU layer: 32 steps, no cache-flush fences ----------------
// grid = 256 blocks x 512 threads (8 waves). Block owns jh = blk*2 + {0,1}.
// wave w = K-eighth (64 k). h state transposed: hT[k][b] (H x 64) so loads/stores
// are 256B-coalesced. h moves through the coherence point via sc0 sc1 accesses;
// everything else uses normal cached paths (ordered by kernel boundaries).
__global__ __launch_bounds__(512, 2) void k_gru_layer(
        const float* __restrict__ giT,   // (3H, SB), bih already added
        const float* __restrict__ Whh,   // (3H, H)
        const float* __restrict__ bhh,   // (3H)
        float* __restrict__ hTA,         // (H, B) zeroed before launch
        float* __restrict__ hTB,         // (H, B)
        float* __restrict__ yT,          // (H, SB)
        float* __restrict__ hn_out,      // (B, H)
        int* __restrict__ bar) {         // zeroed before launch
    __shared__ float wlds[6 * 512];      // [r=jl*3+g][k]  12 KB
    __shared__ float red[6][8][64];      // 12 KB
    int tid = threadIdx.x;
    int lane = tid & 63;
    int wv = tid >> 6;                   // 0..7 = K-eighth
    int jh = blockIdx.x * 2 + (wv & 1);  // used by update waves (wv<2)
    // stage 6 Whh rows once (reused all 32 steps)
    #pragma unroll
    for (int c = 0; c < 6; ++c)
        wlds[c * 512 + tid] = Whh[(size_t)((c % 3) * 512 + blockIdx.x * 2 + c / 3) * H_DIM + tid];
    __syncthreads();
    float br = bhh[jh], bz = bhh[512 + jh], bn = bhh[1024 + jh];
    const f32x4* wp0 = (const f32x4*)&wlds[0 * 512 + wv * 64];
    const f32x4* wp1 = (const f32x4*)&wlds[1 * 512 + wv * 64];
    const f32x4* wp2 = (const f32x4*)&wlds[2 * 512 + wv * 64];
    const f32x4* wp3 = (const f32x4*)&wlds[3 * 512 + wv * 64];
    const f32x4* wp4 = (const f32x4*)&wlds[4 * 512 + wv * 64];
    const f32x4* wp5 = (const f32x4*)&wlds[5 * 512 + wv * 64];
    float hp_reg = 0.0f;                 // h[jh][lane] carried in-register (h0 = 0)
    for (int t = 0; t < 32; ++t) {
        const float* hr = (t & 1) ? hTB : hTA;
        float* hw = (t & 1) ? hTA : hTB;
        // --- coherent load of this wave's K-eighth of h: 64 coalesced dwords ---
        float hreg[64];
        const float* hb0 = hr + (size_t)(wv * 64) * 64 + lane;
        const float* hb1 = hb0 + 1024;
        const float* hb2 = hb0 + 2048;
        const float* hb3 = hb0 + 3072;
        HLD16(hreg, 0, hb0); HLD16(hreg, 16, hb1);
        HLD16(hreg, 32, hb2); HLD16(hreg, 48, hb3);
        asm volatile("s_waitcnt vmcnt(0)" ::: "memory");
        __builtin_amdgcn_sched_barrier(0);
        // --- partial dots: 6 rows (2 jh x 3 gates) over 64 k ---
        float a0=0,a1=0,a2=0,a3=0,a4=0,a5=0;
        #pragma unroll
        for (int q = 0; q < 16; ++q) {
            float h0 = hreg[4*q], h1 = hreg[4*q+1], h2 = hreg[4*q+2], h3 = hreg[4*q+3];
            f32x4 v0 = wp0[q], v1 = wp1[q], v2 = wp2[q], v3 = wp3[q], v4 = wp4[q], v5 = wp5[q];
            a0 += h0*v0.x + h1*v0.y + h2*v0.z + h3*v0.w;
            a1 += h0*v1.x + h1*v1.y + h2*v1.z + h3*v1.w;
            a2 += h0*v2.x + h1*v2.y + h2*v2.z + h3*v2.w;
            a3 += h0*v3.x + h1*v3.y + h2*v3.z + h3*v3.w;
            a4 += h0*v4.x + h1*v4.y + h2*v4.z + h3*v4.w;
            a5 += h0*v5.x + h1*v5.y + h2*v5.z + h3*v5.w;
        }
        red[0][wv][lane] = a0; red[1][wv][lane] = a1; red[2][wv][lane] = a2;
        red[3][wv][lane] = a3; red[4][wv][lane] = a4; red[5][wv][lane] = a5;
        __syncthreads();
        // --- gate update (waves 0,1 = jl 0,1), coherent h store ---
        if (wv < 2) {
            float ar = 0, az = 0, an = 0;
            #pragma unroll
            for (int q = 0; q < 8; ++q) {
                ar += red[wv * 3 + 0][q][lane];
                az += red[wv * 3 + 1][q][lane];
                an += red[wv * 3 + 2][q][lane];
            }
            int col = t * 64 + lane;
            float gr = giT[(size_t)jh * SB + col];
            float gz = giT[(size_t)(512 + jh) * SB + col];
            float gn = giT[(size_t)(1024 + jh) * SB + col];
            float rr = 1.0f / (1.0f + __expf(-(gr + ar + br)));
            float zz = 1.0f / (1.0f + __expf(-(gz + az + bz)));
            float nn = tanhf(gn + rr * (an + bn));
            float h = (1.0f - zz) * nn + zz * hp_reg;
            hp_reg = h;
            HST(h, hw + jh * 64 + lane);     // to coherence point
            yT[(size_t)jh * SB + col] = h;   // plain (read by later kernels)
            if (t == 31) hn_out[lane * H_DIM + jh] = h;
            asm volatile("s_waitcnt vmcnt(0)" ::: "memory");
        }
        __syncthreads();   // all stores at coherence point before arrival
        if (tid == 0) {
            __hip_atomic_fetch_add(bar, 1, __ATOMIC_RELAXED, __HIP_MEMORY_SCOPE_AGENT);
            int tgt = (t + 1) * GRUB;
            while (__hip_atomic_load(bar, __ATOMIC_RELAXED, __HIP_MEMORY_SCOPE_AGENT) < tgt)
                __builtin_amdgcn_s_sleep(2);
        }
        __syncthreads();
    }
}

// ---------------- final linear: out[sb] = dot(y2T[:,sb], Wlin) + blin ----------------
__global__ void k_final(const float* __restrict__ y2T, const float* __restrict__ Wlin,
                        const float* __restrict__ blin, float* __restrict__ outp) {
    int sb = blockIdx.x * 256 + threadIdx.x;
    float acc = blin[0];
    for (int k = 0; k < H_DIM; ++k)
        acc += y2T[(size_t)k * SB + sb] * Wlin[k];
    outp[sb] = acc;
}

extern "C" void kernel_launch(void* const* d_in, const int* in_sizes, int n_in,
                              void* d_out, int out_size, void* d_ws, size_t ws_size,
                              hipStream_t stream) {
    (void)in_sizes; (void)n_in; (void)out_size; (void)ws_size;
    const float* x     = (const float*)d_in[0];
    const int*   ei    = (const int*)d_in[1];
    const float* W1    = (const float*)d_in[2];
    const float* b1    = (const float*)d_in[3];
    const float* W2    = (const float*)d_in[4];
    const float* b2    = (const float*)d_in[5];
    const float* gamma = (const float*)d_in[6];
    const float* beta  = (const float*)d_in[7];
    const float* rmean = (const float*)d_in[8];
    const float* rvar  = (const float*)d_in[9];
    const float* Wih0  = (const float*)d_in[10];
    const float* Whh0  = (const float*)d_in[11];
    const float* bih0  = (const float*)d_in[12];
    const float* bhh0  = (const float*)d_in[13];
    const float* Wih1  = (const float*)d_in[14];
    const float* Whh1  = (const float*)d_in[15];
    const float* bih1  = (const float*)d_in[16];
    const float* bhh1  = (const float*)d_in[17];
    const float* Wlin  = (const float*)d_in[18];
    const float* blin  = (const float*)d_in[19];
    float* outp = (float*)d_out;

    char* w = (char*)d_ws;
    auto alloc = [&](size_t bytes) { char* p = w; w += (bytes + 255) & ~(size_t)255; return p; };
    float*          zbuf   = (float*)alloc((size_t)N_DIM * SB * 4);   // z -> gi0
    float*          h1buf  = (float*)alloc((size_t)N_DIM * SB * 4);   // h1 -> o_bf16 -> gi1
    float*          giT    = (float*)alloc((size_t)H3 * SB * 4);
    unsigned short* wih0b  = (unsigned short*)alloc((size_t)H3 * N_DIM * 2);
    unsigned short* wih1b  = (unsigned short*)alloc((size_t)H3 * H_DIM * 2);
    float*          y1T    = (float*)alloc((size_t)H_DIM * SB * 4);   // also y2T
    unsigned short* y1b    = (unsigned short*)alloc((size_t)SB * H_DIM * 2);
    float*          hTA    = (float*)alloc(H_DIM * B_DIM * 4);
    float*          hTB    = (float*)alloc(H_DIM * B_DIM * 4);
    float*          dinv   = (float*)alloc(N_DIM * 4);
    int*            degcnt = (int*)alloc(N_DIM * 4);
    int*            rowptr = (int*)alloc((N_DIM + 1) * 4);
    int*            cursor = (int*)alloc(N_DIM * 4);
    int*            cols   = (int*)alloc(E_DIM * 4);
    int*            bar0   = (int*)alloc(256);
    int*            bar1   = (int*)alloc(256);
    unsigned short* obf    = (unsigned short*)h1buf;

    hipMemsetAsync(degcnt, 0, N_DIM * 4, stream);
    hipMemsetAsync(cursor, 0, N_DIM * 4, stream);
    hipMemsetAsync(hTA, 0, H_DIM * B_DIM * 4, stream);
    hipMemsetAsync(bar0, 0, 256, stream);
    hipMemsetAsync(bar1, 0, 256, stream);

    k_gcn1_dot<<<1024, 256, 0, stream>>>(x, W1, zbuf);
    k_degcnt<<<E_DIM / 256, 256, 0, stream>>>(ei, degcnt);
    k_dinv<<<N_DIM / 256, 256, 0, stream>>>(degcnt, dinv);
    k_scan<<<1, 1024, 0, stream>>>(degcnt, rowptr);
    k_fill<<<E_DIM / 256, 256, 0, stream>>>(ei, rowptr, cursor, cols);

    k_spmm<<<16384, 256, 0, stream>>>(zbuf, h1buf, rowptr, cols, dinv, 0, b1, (const float*)nullptr,
                                      gamma, beta, rmean, rvar);
    k_spmm<<<16384, 256, 0, stream>>>(h1buf, zbuf, rowptr, cols, dinv, 1, b2, W2,
                                      gamma, beta, rmean, rvar);
    k_transpose_cvt<<<(N_DIM / 64) * (SB / 64), 256, 0, stream>>>(zbuf, obf, N_DIM, SB);
    k_cvt_bf16<<<(H3 * N_DIM / 4) / 256, 256, 0, stream>>>(Wih0, wih0b, H3 * N_DIM);
    k_cvt_bf16<<<(H3 * H_DIM / 4) / 256, 256, 0, stream>>>(Wih1, wih1b, H3 * H_DIM);

    float* gi0 = zbuf;
    k_gemm_bf16<<<(SB / BM) * (H3 / BN), 256, 0, stream>>>(obf, wih0b, bih0, gi0, SB, H3, N_DIM);
    k_transpose_f32<<<(SB / 64) * (H3 / 64), 256, 0, stream>>>(gi0, giT, SB, H3);

    k_gru_layer<<<GRUB, 512, 0, stream>>>(giT, Whh0, bhh0, hTA, hTB, y1T, outp + 2048, bar0);

    k_transpose_cvt<<<(H_DIM / 64) * (SB / 64), 256, 0, stream>>>(y1T, y1b, H_DIM, SB);
    float* gi1 = h1buf;
    k_gemm_bf16<<<(SB / BM) * (H3 / BN), 256, 0, stream>>>(y1b, wih1b, bih1, gi1, SB, H3, H_DIM);
    k_transpose_f32<<<(SB / 64) * (H3 / 64), 256, 0, stream>>>(gi1, giT, SB, H3);

    hipMemsetAsync(hTA, 0, H_DIM * B_DIM * 4, stream);
    k_gru_layer<<<GRUB, 512, 0, stream>>>(giT, Whh1, bhh1, hTA, hTB, y1T, outp + 2048 + 32768, bar1);

    k_final<<<SB / 256, 256, 0, stream>>>(y1T, Wlin, blin, outp);
}

// Round 7
// 1098.439 us; speedup vs baseline: 4.7927x; 1.0748x over previous
//
#include <hip/hip_runtime.h>
#include <stdint.h>

#define S_DIM 32
#define B_DIM 64
#define N_DIM 2048
#define F_DIM 16
#define E_DIM 32768
#define H_DIM 512
#define H3 1536
#define SB 2048
#define EPS_BN 1e-5f
#define GRUB 256   // persistent GRU grid; must be <= 256 so all blocks are co-resident

typedef __attribute__((ext_vector_type(4))) float f32x4;
typedef __attribute__((ext_vector_type(8))) __bf16 bf16x8;

static __device__ __forceinline__ unsigned short f2bf(float f) {
    union { float f; unsigned int u; } v; v.f = f;
    unsigned int r = v.u + 0x7FFFu + ((v.u >> 16) & 1u);
    return (unsigned short)(r >> 16);
}

// coherent (agent-scope, cache-bypassing) scalar load/store: sc0 sc1 = coherence point
#define HLD(dst, base, OFF) \
    asm volatile("global_load_dword %0, %1, off offset:" #OFF " sc0 sc1" : "=v"(dst) : "v"(base))
#define HLD16(A, I, base) \
    HLD(A[I+0],base,0);    HLD(A[I+1],base,256);  HLD(A[I+2],base,512);  HLD(A[I+3],base,768); \
    HLD(A[I+4],base,1024); HLD(A[I+5],base,1280); HLD(A[I+6],base,1536); HLD(A[I+7],base,1792); \
    HLD(A[I+8],base,2048); HLD(A[I+9],base,2304); HLD(A[I+10],base,2560);HLD(A[I+11],base,2816);\
    HLD(A[I+12],base,3072);HLD(A[I+13],base,3328);HLD(A[I+14],base,3584);HLD(A[I+15],base,3840)
#define HST(val, addr) \
    asm volatile("global_store_dword %0, %1, off sc0 sc1" :: "v"(addr), "v"(val) : "memory")

// ---------------- GCN stage 1: z[n][sb] = dot(x[sb,n,:], W1) ----------------
__global__ __launch_bounds__(256) void k_gcn1_dot(const float* __restrict__ x,
        const float* __restrict__ W1, float* __restrict__ z) {
    __shared__ float tile[64][65];
    int bn = blockIdx.x & 31;
    int bs = blockIdx.x >> 5;
    int n0 = bn * 64, sb0 = bs * 64;
    float4 w0 = *(const float4*)&W1[0];
    float4 w1 = *(const float4*)&W1[4];
    float4 w2 = *(const float4*)&W1[8];
    float4 w3 = *(const float4*)&W1[12];
    int t = threadIdx.x;
    for (int i = 0; i < 16; ++i) {
        int idx = t + 256 * i;
        int nl = idx & 63, sl = idx >> 6;
        const float4* xv = (const float4*)(x + ((size_t)(sb0 + sl) * N_DIM + (n0 + nl)) * F_DIM);
        float4 a = xv[0], b = xv[1], c = xv[2], d = xv[3];
        float acc = a.x*w0.x + a.y*w0.y + a.z*w0.z + a.w*w0.w
                  + b.x*w1.x + b.y*w1.y + b.z*w1.z + b.w*w1.w
                  + c.x*w2.x + c.y*w2.y + c.z*w2.z + c.w*w2.w
                  + d.x*w3.x + d.y*w3.y + d.z*w3.z + d.w*w3.w;
        tile[nl][sl] = acc;
    }
    __syncthreads();
    for (int i = 0; i < 16; ++i) {
        int idx = t + 256 * i;
        int sl = idx & 63, nl = idx >> 6;
        z[(size_t)(n0 + nl) * SB + sb0 + sl] = tile[nl][sl];
    }
}

// ---------------- CSR build ----------------
__global__ void k_degcnt(const int* __restrict__ ei, int* __restrict__ cnt) {
    int e = blockIdx.x * 256 + threadIdx.x;
    if (e < E_DIM) atomicAdd(&cnt[ei[E_DIM + e]], 1);
}
__global__ void k_scan(const int* __restrict__ cnt, int* __restrict__ rowptr,
                       float* __restrict__ dinv) {
    __shared__ int sc[2048];
    int t = threadIdx.x;
    int c0 = cnt[t], c1 = cnt[t + 1024];
    sc[t] = c0; sc[t + 1024] = c1;
    __syncthreads();
    for (int off = 1; off < 2048; off <<= 1) {
        int a = (t >= off) ? sc[t - off] : 0;
        int b = (t + 1024 >= off) ? sc[t + 1024 - off] : 0;
        __syncthreads();
        sc[t] += a; sc[t + 1024] += b;
        __syncthreads();
    }
    rowptr[t] = sc[t] - c0;
    rowptr[t + 1024] = sc[t + 1024] - c1;
    if (t == 0) rowptr[2048] = E_DIM;
    dinv[t] = rsqrtf(1.0f + (float)c0);
    dinv[t + 1024] = rsqrtf(1.0f + (float)c1);
}
__global__ void k_fill(const int* __restrict__ ei, const int* __restrict__ rowptr,
                       int* __restrict__ cursor, int* __restrict__ cols) {
    int e = blockIdx.x * 256 + threadIdx.x;
    if (e < E_DIM) {
        int d = ei[E_DIM + e];
        int pos = atomicAdd(&cursor[d], 1);
        cols[rowptr[d] + pos] = ei[e];
    }
}

// ---------------- SpMM (gather). mode0: sigmoid(acc+b1). mode1: BN(w2*acc+b2) ----------------
__global__ __launch_bounds__(256) void k_spmm(const float* __restrict__ in,
        float* __restrict__ outp, const int* __restrict__ rowptr, const int* __restrict__ cols,
        const float* __restrict__ dinv, int mode,
        const float* __restrict__ bp, const float* __restrict__ w2p,
        const float* __restrict__ gamma, const float* __restrict__ beta,
        const float* __restrict__ rmean, const float* __restrict__ rvar) {
    int n = blockIdx.x & 2047;
    int sb = ((blockIdx.x >> 11) << 8) + threadIdx.x;
    float dn = dinv[n];
    float acc = dn * dn * in[(size_t)n * SB + sb];
    int i0 = rowptr[n], i1 = rowptr[n + 1];
    for (int idx = i0; idx < i1; ++idx) {
        int s = cols[idx];
        acc += dn * dinv[s] * in[(size_t)s * SB + sb];
    }
    float v;
    if (mode == 0) {
        v = acc + bp[0];
        v = 1.0f / (1.0f + __expf(-v));
    } else {
        v = w2p[0] * acc + bp[0];
        v = (v - rmean[n]) * rsqrtf(rvar[n] + EPS_BN) * gamma[n] + beta[n];
    }
    outp[(size_t)n * SB + sb] = v;
}

// ---------------- transpose + fp32->bf16: in (R,C) f32 -> out (C,R) bf16 ----------------
__global__ __launch_bounds__(256) void k_transpose_cvt(const float* __restrict__ in,
        unsigned short* __restrict__ outp, int R, int C) {
    __shared__ float tile[64][65];
    int nrt = R >> 6;
    int rt = blockIdx.x % nrt;
    int ct = blockIdx.x / nrt;
    int r0 = rt * 64, c0 = ct * 64;
    int t = threadIdx.x;
    for (int i = 0; i < 16; ++i) {
        int idx = t + i * 256;
        int cl = idx & 63, rl = idx >> 6;
        tile[rl][cl] = in[(size_t)(r0 + rl) * C + c0 + cl];
    }
    __syncthreads();
    for (int i = 0; i < 16; ++i) {
        int idx = t + i * 256;
        int rl = idx & 63, cl = idx >> 6;
        outp[(size_t)(c0 + cl) * R + r0 + rl] = f2bf(tile[rl][cl]);
    }
}

// ---------------- elementwise fp32 -> bf16 ----------------
__global__ void k_cvt_bf16(const float* __restrict__ in, unsigned short* __restrict__ outp, int nelem) {
    int i = (blockIdx.x * 256 + threadIdx.x) * 4;
    if (i < nelem) {
        float4 v = *(const float4*)&in[i];
        ushort4 o;
        o.x = f2bf(v.x); o.y = f2bf(v.y); o.z = f2bf(v.z); o.w = f2bf(v.w);
        *(ushort4*)&outp[i] = o;
    }
}

// ---- bf16 MFMA GEMM: CT(N,M) = (A(M,K)*B(N,K)^T + bias(N))^T, 128x64 tile ----
// writes the TRANSPOSED result directly (CT[n][m]) so the GRU reads (3H, SB).
#define BM 128
#define BN 64
#define BKK 32
#define LDT 40

__global__ __launch_bounds__(256) void k_gemm_bf16_t(
        const unsigned short* __restrict__ A,
        const unsigned short* __restrict__ Bm,
        const float* __restrict__ bias,
        float* __restrict__ CT, int M, int N, int K) {
    __shared__ __align__(16) unsigned short lA[BM * LDT];
    __shared__ __align__(16) unsigned short lB[BN * LDT];
    int mtiles = M / BM;
    int mt = blockIdx.x % mtiles;
    int nt = blockIdx.x / mtiles;
    int m0 = mt * BM, n0 = nt * BN;
    int t = threadIdx.x;
    int wave = t >> 6, lane = t & 63;
    int wm = (wave >> 1) * 64, wn = (wave & 1) * 32;
    int lrow = lane & 15, lk = (lane >> 4) * 8;
    int srowA = t >> 1, scolA = (t & 1) * 16;
    int srowB = t >> 2, scolB = (t & 3) * 8;
    f32x4 acc[4][2] = {};
    for (int k0 = 0; k0 < K; k0 += BKK) {
        const unsigned short* ga = A  + (size_t)(m0 + srowA) * K + k0 + scolA;
        const unsigned short* gb = Bm + (size_t)(n0 + srowB) * K + k0 + scolB;
        *(uint4*)&lA[srowA * LDT + scolA]     = *(const uint4*)ga;
        *(uint4*)&lA[srowA * LDT + scolA + 8] = *(const uint4*)(ga + 8);
        *(uint4*)&lB[srowB * LDT + scolB]     = *(const uint4*)gb;
        __syncthreads();
        bf16x8 af[4], bg[2];
        #pragma unroll
        for (int i = 0; i < 4; ++i)
            af[i] = *(const bf16x8*)&lA[(wm + i * 16 + lrow) * LDT + lk];
        #pragma unroll
        for (int j = 0; j < 2; ++j)
            bg[j] = *(const bf16x8*)&lB[(wn + j * 16 + lrow) * LDT + lk];
        #pragma unroll
        for (int i = 0; i < 4; ++i)
            #pragma unroll
            for (int j = 0; j < 2; ++j)
                acc[i][j] = __builtin_amdgcn_mfma_f32_16x16x32_bf16(af[i], bg[j], acc[i][j], 0, 0, 0);
        __syncthreads();
    }
    int crow = (lane >> 4) * 4, ccol = lane & 15;
    #pragma unroll
    for (int i = 0; i < 4; ++i)
        #pragma unroll
        for (int j = 0; j < 2; ++j) {
            int gn = n0 + wn + j * 16 + ccol;
            int gm = m0 + wm + i * 16 + crow;
            float bv = bias[gn];
            float4 v;
            v.x = acc[i][j][0] + bv; v.y = acc[i][j][1] + bv;
            v.z = acc[i][j][2] + bv; v.w = acc[i][j][3] + bv;
            *(float4*)&CT[(size_t)gn * M + gm] = v;
        }
}

// ---------------- persistent GRU layer: 32 steps, tree barrier ----------------
// grid = 256 blocks x 512 threads (8 waves). Block owns jh = blk*2 + {0,1}.
// wave wv = K-eighth. h state (H, B): sc0sc1 coherent accesses only for h.
// barrier: 8 leaf counters (128B apart) -> root -> epoch flag; all poll epoch.
__global__ __launch_bounds__(512, 2) void k_gru_layer(
        const float* __restrict__ giT,   // (3H, SB), bih already added
        const float* __restrict__ Whh,   // (3H, H)
        const float* __restrict__ bhh,   // (3H)
        float* __restrict__ hTA,         // (H, B) zeroed before launch
        float* __restrict__ hTB,         // (H, B)
        float* __restrict__ yT,          // (H, SB)
        float* __restrict__ hn_out,      // (B, H)
        int* __restrict__ bar) {         // 2KB zeroed: [0]=epoch [16]=root [32+g*32]=leaf g
    __shared__ float wlds[6 * 512];      // [r=jl*3+g][k]  12 KB
    __shared__ float red[6][8][64];      // 12 KB
    int tid = threadIdx.x;
    int lane = tid & 63;
    int wv = tid >> 6;                   // 0..7 = K-eighth
    int jh = blockIdx.x * 2 + (wv & 1);  // used by update waves (wv<2)
    #pragma unroll
    for (int c = 0; c < 6; ++c)
        wlds[c * 512 + tid] = Whh[(size_t)((c % 3) * 512 + blockIdx.x * 2 + c / 3) * H_DIM + tid];
    __syncthreads();
    float br = bhh[jh], bz = bhh[512 + jh], bn = bhh[1024 + jh];
    const f32x4* wp0 = (const f32x4*)&wlds[0 * 512 + wv * 64];
    const f32x4* wp1 = (const f32x4*)&wlds[1 * 512 + wv * 64];
    const f32x4* wp2 = (const f32x4*)&wlds[2 * 512 + wv * 64];
    const f32x4* wp3 = (const f32x4*)&wlds[3 * 512 + wv * 64];
    const f32x4* wp4 = (const f32x4*)&wlds[4 * 512 + wv * 64];
    const f32x4* wp5 = (const f32x4*)&wlds[5 * 512 + wv * 64];
    int* leaf = bar + 32 + ((blockIdx.x >> 5) << 5);
    float hp_reg = 0.0f;                 // h[jh][lane] carried in-register (h0 = 0)
    for (int t = 0; t < 32; ++t) {
        const float* hr = (t & 1) ? hTB : hTA;
        float* hw = (t & 1) ? hTA : hTB;
        // prefetch gi for this step (independent of h; drains with the vmcnt(0) below)
        float gr_p = 0.f, gz_p = 0.f, gn_p = 0.f;
        int col = t * 64 + lane;
        if (wv < 2) {
            gr_p = giT[(size_t)jh * SB + col];
            gz_p = giT[(size_t)(512 + jh) * SB + col];
            gn_p = giT[(size_t)(1024 + jh) * SB + col];
        }
        // coherent load of this wave's K-eighth of h: 64 coalesced dwords
        float hreg[64];
        const float* hb0 = hr + (size_t)(wv * 64) * 64 + lane;
        const float* hb1 = hb0 + 1024;
        const float* hb2 = hb0 + 2048;
        const float* hb3 = hb0 + 3072;
        HLD16(hreg, 0, hb0); HLD16(hreg, 16, hb1);
        HLD16(hreg, 32, hb2); HLD16(hreg, 48, hb3);
        asm volatile("s_waitcnt vmcnt(0)" ::: "memory");
        __builtin_amdgcn_sched_barrier(0);
        // partial dots: 6 rows (2 jh x 3 gates) over this wave's 64 k
        float a0=0,a1=0,a2=0,a3=0,a4=0,a5=0;
        #pragma unroll
        for (int q = 0; q < 16; ++q) {
            float h0 = hreg[4*q], h1 = hreg[4*q+1], h2 = hreg[4*q+2], h3 = hreg[4*q+3];
            f32x4 v0 = wp0[q], v1 = wp1[q], v2 = wp2[q], v3 = wp3[q], v4 = wp4[q], v5 = wp5[q];
            a0 += h0*v0.x + h1*v0.y + h2*v0.z + h3*v0.w;
            a1 += h0*v1.x + h1*v1.y + h2*v1.z + h3*v1.w;
            a2 += h0*v2.x + h1*v2.y + h2*v2.z + h3*v2.w;
            a3 += h0*v3.x + h1*v3.y + h2*v3.z + h3*v3.w;
            a4 += h0*v4.x + h1*v4.y + h2*v4.z + h3*v4.w;
            a5 += h0*v5.x + h1*v5.y + h2*v5.z + h3*v5.w;
        }
        red[0][wv][lane] = a0; red[1][wv][lane] = a1; red[2][wv][lane] = a2;
        red[3][wv][lane] = a3; red[4][wv][lane] = a4; red[5][wv][lane] = a5;
        __syncthreads();
        // gate update (waves 0,1), coherent h store only (yT deferred past arrival)
        float h_new = 0.f;
        if (wv < 2) {
            float ar = 0, az = 0, an = 0;
            #pragma unroll
            for (int q = 0; q < 8; ++q) {
                ar += red[wv * 3 + 0][q][lane];
                az += red[wv * 3 + 1][q][lane];
                an += red[wv * 3 + 2][q][lane];
            }
            float rr = 1.0f / (1.0f + __expf(-(gr_p + ar + br)));
            float zz = 1.0f / (1.0f + __expf(-(gz_p + az + bz)));
            float nn = tanhf(gn_p + rr * (an + bn));
            h_new = (1.0f - zz) * nn + zz * hp_reg;
            hp_reg = h_new;
            HST(h_new, hw + jh * 64 + lane);     // to coherence point
            asm volatile("s_waitcnt vmcnt(0)" ::: "memory");
        }
        __syncthreads();   // all h stores at coherence point before arrival
        if (tid == 0) {    // tree arrival: leaf (32/line) -> root (8) -> epoch
            int old = __hip_atomic_fetch_add(leaf, 1, __ATOMIC_RELAXED, __HIP_MEMORY_SCOPE_AGENT);
            if ((old & 31) == 31) {
                int r = __hip_atomic_fetch_add(bar + 16, 1, __ATOMIC_RELAXED, __HIP_MEMORY_SCOPE_AGENT);
                if ((r & 7) == 7)
                    __hip_atomic_store(bar, t + 1, __ATOMIC_RELAXED, __HIP_MEMORY_SCOPE_AGENT);
            }
        }
        // overlap with polling: yT / hn_out are only read after kernel end
        if (wv < 2) {
            yT[(size_t)jh * SB + col] = h_new;
            if (t == 31) hn_out[lane * H_DIM + jh] = h_new;
        }
        if (tid == 0) {
            while (__hip_atomic_load(bar, __ATOMIC_RELAXED, __HIP_MEMORY_SCOPE_AGENT) < t + 1)
                __builtin_amdgcn_s_sleep(2);
        }
        __syncthreads();
    }
}

// ---------------- final linear: out[sb] = dot(y2T[:,sb], Wlin) + blin ----------------
__global__ void k_final(const float* __restrict__ y2T, const float* __restrict__ Wlin,
                        const float* __restrict__ blin, float* __restrict__ outp) {
    int sb = blockIdx.x * 256 + threadIdx.x;
    float acc = blin[0];
    for (int k = 0; k < H_DIM; ++k)
        acc += y2T[(size_t)k * SB + sb] * Wlin[k];
    outp[sb] = acc;
}

extern "C" void kernel_launch(void* const* d_in, const int* in_sizes, int n_in,
                              void* d_out, int out_size, void* d_ws, size_t ws_size,
                              hipStream_t stream) {
    (void)in_sizes; (void)n_in; (void)out_size; (void)ws_size;
    const float* x     = (const float*)d_in[0];
    const int*   ei    = (const int*)d_in[1];
    const float* W1    = (const float*)d_in[2];
    const float* b1    = (const float*)d_in[3];
    const float* W2    = (const float*)d_in[4];
    const float* b2    = (const float*)d_in[5];
    const float* gamma = (const float*)d_in[6];
    const float* beta  = (const float*)d_in[7];
    const float* rmean = (const float*)d_in[8];
    const float* rvar  = (const float*)d_in[9];
    const float* Wih0  = (const float*)d_in[10];
    const float* Whh0  = (const float*)d_in[11];
    const float* bih0  = (const float*)d_in[12];
    const float* bhh0  = (const float*)d_in[13];
    const float* Wih1  = (const float*)d_in[14];
    const float* Whh1  = (const float*)d_in[15];
    const float* bih1  = (const float*)d_in[16];
    const float* bhh1  = (const float*)d_in[17];
    const float* Wlin  = (const float*)d_in[18];
    const float* blin  = (const float*)d_in[19];
    float* outp = (float*)d_out;

    char* w = (char*)d_ws;
    auto alloc = [&](size_t bytes) { char* p = w; w += (bytes + 255) & ~(size_t)255; return p; };
    float*          zbuf   = (float*)alloc((size_t)N_DIM * SB * 4);   // z (oT)
    float*          h1buf  = (float*)alloc((size_t)N_DIM * SB * 4);   // h1 -> o_bf16
    float*          giT    = (float*)alloc((size_t)H3 * SB * 4);      // gates, transposed
    unsigned short* wih0b  = (unsigned short*)alloc((size_t)H3 * N_DIM * 2);
    unsigned short* wih1b  = (unsigned short*)alloc((size_t)H3 * H_DIM * 2);
    float*          y1T    = (float*)alloc((size_t)H_DIM * SB * 4);   // also y2T
    unsigned short* y1b    = (unsigned short*)alloc((size_t)SB * H_DIM * 2);
    float*          hTA    = (float*)alloc(H_DIM * B_DIM * 4);
    float*          hTB    = (float*)alloc(H_DIM * B_DIM * 4);
    float*          dinv   = (float*)alloc(N_DIM * 4);
    int*            degcnt = (int*)alloc(N_DIM * 4);
    int*            rowptr = (int*)alloc((N_DIM + 1) * 4);
    int*            cursor = (int*)alloc(N_DIM * 4);
    int*            cols   = (int*)alloc(E_DIM * 4);
    int*            bar0   = (int*)alloc(2048);
    int*            bar1   = (int*)alloc(2048);
    unsigned short* obf    = (unsigned short*)h1buf;

    hipMemsetAsync(degcnt, 0, N_DIM * 4, stream);
    hipMemsetAsync(cursor, 0, N_DIM * 4, stream);
    hipMemsetAsync(hTA, 0, H_DIM * B_DIM * 4, stream);
    hipMemsetAsync(bar0, 0, 2048, stream);
    hipMemsetAsync(bar1, 0, 2048, stream);

    k_gcn1_dot<<<1024, 256, 0, stream>>>(x, W1, zbuf);
    k_degcnt<<<E_DIM / 256, 256, 0, stream>>>(ei, degcnt);
    k_scan<<<1, 1024, 0, stream>>>(degcnt, rowptr, dinv);
    k_fill<<<E_DIM / 256, 256, 0, stream>>>(ei, rowptr, cursor, cols);

    k_spmm<<<16384, 256, 0, stream>>>(zbuf, h1buf, rowptr, cols, dinv, 0, b1, (const float*)nullptr,
                                      gamma, beta, rmean, rvar);
    k_spmm<<<16384, 256, 0, stream>>>(h1buf, zbuf, rowptr, cols, dinv, 1, b2, W2,
                                      gamma, beta, rmean, rvar);
    k_transpose_cvt<<<(N_DIM / 64) * (SB / 64), 256, 0, stream>>>(zbuf, obf, N_DIM, SB);
    k_cvt_bf16<<<(H3 * N_DIM / 4) / 256, 256, 0, stream>>>(Wih0, wih0b, H3 * N_DIM);
    k_cvt_bf16<<<(H3 * H_DIM / 4) / 256, 256, 0, stream>>>(Wih1, wih1b, H3 * H_DIM);

    // giT = (o @ Wih0^T + bih0)^T  directly in (3H, SB)
    k_gemm_bf16_t<<<(SB / BM) * (H3 / BN), 256, 0, stream>>>(obf, wih0b, bih0, giT, SB, H3, N_DIM);

    k_gru_layer<<<GRUB, 512, 0, stream>>>(giT, Whh0, bhh0, hTA, hTB, y1T, outp + 2048, bar0);

    k_transpose_cvt<<<(H_DIM / 64) * (SB / 64), 256, 0, stream>>>(y1T, y1b, H_DIM, SB);
    k_gemm_bf16_t<<<(SB / BM) * (H3 / BN), 256, 0, stream>>>(y1b, wih1b, bih1, giT, SB, H3, H_DIM);

    hipMemsetAsync(hTA, 0, H_DIM * B_DIM * 4, stream);
    k_gru_layer<<<GRUB, 512, 0, stream>>>(giT, Whh1, bhh1, hTA, hTB, y1T, outp + 2048 + 32768, bar1);

    k_final<<<SB / 256, 256, 0, stream>>>(y1T, Wlin, blin, outp);
}